// Round 6
// baseline (232.232 us; speedup 1.0000x reference)
//
#include <hip/hip_runtime.h>
#include <stdint.h>

#define B_ 8
#define C_ 256
#define N_ 4096

typedef __attribute__((ext_vector_type(8))) short short8;
typedef __attribute__((ext_vector_type(4))) float float4v;
typedef __attribute__((ext_vector_type(16))) float floatx16;

__device__ __forceinline__ uint16_t f2bfr(float f) {
  return (uint16_t)((__float_as_uint(f) + 0x8000u) >> 16);
}
__device__ __forceinline__ uint32_t pkbf(float lo, float hi) {
  return ((__float_as_uint(hi) + 0x8000u) & 0xffff0000u) |
         ((__float_as_uint(lo) + 0x8000u) >> 16);
}
// 16B LDS read as 2x b64 (rows 280B-strided: dw-stride 70 == 6 mod 32,
// gcd(6,32)=2 -> 2-way bank aliasing == free per m136.)
__device__ __forceinline__ short8 ld8(const uint16_t* p) {
  union { ushort4 h[2]; short8 v; } u;
  u.h[0] = *reinterpret_cast<const ushort4*>(p);
  u.h[1] = *reinterpret_cast<const ushort4*>(p + 4);
  return u.v;
}

// ---------------------------------------------------------------------------
// Kernel 0: W fp32 -> Wc bf16, biases fp32.
// ---------------------------------------------------------------------------
__global__ __launch_bounds__(256) void wconv_kernel(
    const float* __restrict__ Wq, const float* __restrict__ bq,
    const float* __restrict__ Wk, const float* __restrict__ bk,
    const float* __restrict__ Wv, const float* __restrict__ bv,
    uint16_t* __restrict__ Wc, float* __restrict__ bc)
{
  int tg = blockIdx.x * 256 + threadIdx.x;
  int idx = tg * 4;
  const float* src = (idx < 8192) ? (Wq + idx)
                   : (idx < 16384) ? (Wk + (idx - 8192))
                                   : (Wv + (idx - 16384));
  float4 wv = *reinterpret_cast<const float4*>(src);
  uint2 o;
  o.x = pkbf(wv.x, wv.y);
  o.y = pkbf(wv.z, wv.w);
  *reinterpret_cast<uint2*>(Wc + idx) = o;
  if (tg < 320) bc[tg] = (tg < 32) ? bq[tg] : (tg < 64) ? bk[tg - 32] : bv[tg - 64];
}

// ---------------------------------------------------------------------------
// Kernel 1: QKV via MFMA. 1-D grid, XCD-pinned (b = blockIdx.x & 7).
// Unchanged from round 4.
// ---------------------------------------------------------------------------
__global__ __launch_bounds__(512, 4) void qkv_mfma(
    const float* __restrict__ x, const uint16_t* __restrict__ Wc,
    const float* __restrict__ bc,
    uint16_t* __restrict__ Qw, uint16_t* __restrict__ Kw, uint16_t* __restrict__ Vw)
{
  __shared__ __align__(16) uint16_t xs[64][268];
  const int b = blockIdx.x & 7;         // XCD pin
  const int tile = blockIdx.x >> 3;
  const int n0 = tile * 64;
  const int tid = threadIdx.x;
  const int nl = tid & 63, grp = tid >> 6;
  const int w = grp, l15 = tid & 15, q = (tid & 63) >> 4;
  const int nb = w & 3;

  const float* xb = x + (size_t)b * C_ * N_ + n0;
  #pragma unroll
  for (int it = 0; it < 16; ++it) {
    int c2 = it * 16 + grp * 2;
    float f0 = xb[(size_t)c2 * N_ + nl];
    float f1 = xb[(size_t)(c2 + 1) * N_ + nl];
    *reinterpret_cast<uint32_t*>(&xs[nl][c2]) = pkbf(f0, f1);
  }
  __syncthreads();

  float4v acc[10];
  #pragma unroll
  for (int i = 0; i < 10; ++i) acc[i] = (float4v){0.f, 0.f, 0.f, 0.f};

  const int ob0 = (w >> 2) * 10;
  #pragma unroll
  for (int h2 = 0; h2 < 2; ++h2) {
    short8 bx[4];
    #pragma unroll
    for (int kb = 0; kb < 4; ++kb)
      bx[kb] = ld8(&xs[nb * 16 + l15][h2 * 128 + kb * 32 + q * 8]);
    #pragma unroll
    for (int oi = 0; oi < 10; ++oi) {
      int ob = ob0 + oi;
      const uint16_t* wr = Wc + (size_t)(ob * 16 + l15) * 256 + h2 * 128 + q * 8;
      short8 aw[4];
      #pragma unroll
      for (int kb = 0; kb < 4; ++kb)
        aw[kb] = *reinterpret_cast<const short8*>(wr + kb * 32);
      #pragma unroll
      for (int kb = 0; kb < 4; ++kb)
        acc[oi] = __builtin_amdgcn_mfma_f32_16x16x32_bf16(aw[kb], bx[kb], acc[oi], 0, 0, 0);
    }
  }

  // ---- Q/K epilogue (ob 0..3 live in waves 0-3) via LDS transpose ----
  __syncthreads();
  uint16_t (*qs)[72] = reinterpret_cast<uint16_t(*)[72]>(&xs[0][0]);
  if (w < 4) {
    #pragma unroll
    for (int oi = 0; oi < 4; ++oi) {
      float4v a = acc[oi];
      const float* bb = bc + oi * 16 + q * 4;
      uint2 pk2;
      pk2.x = pkbf(a.x + bb[0], a.y + bb[1]);
      pk2.y = pkbf(a.z + bb[2], a.w + bb[3]);
      *reinterpret_cast<uint2*>(&qs[nb * 16 + l15][oi * 16 + q * 4]) = pk2;
    }
  }
  __syncthreads();
  if (tid < 256) {
    int n = tid >> 2, sub = tid & 3;
    const uint16_t* row = qs[n];
    uint4 d0 = *reinterpret_cast<const uint4*>(&row[sub * 16]);
    uint4 d1 = *reinterpret_cast<const uint4*>(&row[sub * 16 + 8]);
    size_t nn = (size_t)b * N_ + n0 + n;
    if (sub < 2) {
      uint4* dst = reinterpret_cast<uint4*>(Qw + nn * 32 + sub * 16);
      dst[0] = d0; dst[1] = d1;
    } else {
      uint4* dst = reinterpret_cast<uint4*>(Kw + nn * 32 + (sub - 2) * 16);
      dst[0] = d0; dst[1] = d1;
    }
  }
  // ---- V epilogue into swizzled layout ----
  const size_t blk = ((size_t)b * 64 + tile) * 4;
  const int half = l15 >> 3, j = l15 & 7;
  #pragma unroll
  for (int oi = 0; oi < 10; ++oi) {
    int ob = ob0 + oi;
    if (ob < 4) continue;
    float4v a = acc[oi];
    const float* bb = bc + ob * 16 + q * 4;
    int cb = ob * 16 - 64 + q * 4;
    size_t vaddr = (blk + (cb >> 6)) * 4096
                 + (size_t)(nb * 1024 + ((cb >> 5) & 1) * 512 + half * 256
                            + (cb & 31) * 8 + j);
    Vw[vaddr     ] = f2bfr(a.x + bb[0]);
    Vw[vaddr +  8] = f2bfr(a.y + bb[1]);
    Vw[vaddr + 16] = f2bfr(a.z + bb[2]);
    Vw[vaddr + 24] = f2bfr(a.w + bb[3]);
  }
}

// ---------------------------------------------------------------------------
// Kernel 2: MFMA flash attention. 512 thr, grid 512, XCD-pinned.
// Round-6: KVBLK 64 -> 128 (round-4 body style; round-5's hand ping-pong
// REVERTED — it regressed 97->103, second confirmation that hand register
// choreography loses to the compiler here). Same total MFMA/exp/load work,
// HALF the barriers (32 vs 64): the per-iter ~2200cyc non-overlapped stall
// was dominated by barrier convergence + the __syncthreads drain. Wave w now
// owns key-blocks {nb, nb+4}; S-phase = 4 MFMAs; PV = 8 ks-slices. V part2
// is loaded intra-iter (covered by S + PV part1 ~400cyc); V part1 / K keep
// the round-3-validated distance-1 register prefetch. Ps rows 140 uint16
// (280B, 70dw == 6 mod 32 -> same free 2-way bank class as the 76-stride).
// ---------------------------------------------------------------------------
__global__ __launch_bounds__(512, 4) void attn_mfma(
    const uint16_t* __restrict__ Qw, const uint16_t* __restrict__ Kw,
    const uint16_t* __restrict__ Vw, const float* __restrict__ x,
    const float* __restrict__ gamma, float* __restrict__ out)
{
  __shared__ __align__(16) union Smem {
    uint16_t Ps[2][64 * 140];     // 35840 B, rows 280B (70 dw == 6 mod 32)
    float Os[128 * 69];           // 35328 B, stride 69 == 5 mod 32
  } sm;
  __shared__ float Ls[64];

  const int b = blockIdx.x & 7;         // XCD pin (matches qkv)
  const int m0 = (blockIdx.x >> 3) * 64;
  const int tid = threadIdx.x;
  const int w = tid >> 6, lane = tid & 63;
  const int l15 = lane & 15, q = lane >> 4;
  const int l31 = lane & 31, half = lane >> 5;
  const int nb = w & 3, mbp = (w >> 2) * 2;     // S assignment

  const uint16_t* Kb = Kw + (size_t)b * N_ * 32 + (size_t)(nb * 16 + l15) * 32 + q * 8;
  const short8 qf0 = *reinterpret_cast<const short8*>(
      Qw + ((size_t)b * N_ + m0 + (mbp    ) * 16 + l15) * 32 + q * 8);
  const short8 qf1 = *reinterpret_cast<const short8*>(
      Qw + ((size_t)b * N_ + m0 + (mbp + 1) * 16 + l15) * 32 + q * 8);
  // swizzled V: lane offset within (b, tile64, cg) 4096-elem block
  const uint16_t* Vb = Vw + ((size_t)b * 256 + (w >> 1)) * 4096
                     + (w & 1) * 512 + half * 256 + l31 * 8;

  floatx16 O[2];
  #pragma unroll
  for (int i = 0; i < 16; ++i) { O[0][i] = 0.f; O[1][i] = 0.f; }
  float rs0 = 0.f, rs1 = 0.f;
  const float4v zero4 = (float4v){0.f, 0.f, 0.f, 0.f};
  if (tid < 64) Ls[tid] = 0.f;

  // S-phase for one 128-key tile: wave w covers key-blocks nb and nb+4.
  auto s_phase = [&](short8 k0, short8 k1, uint16_t* __restrict__ dst) {
    float4v s0 = __builtin_amdgcn_mfma_f32_16x16x32_bf16(k0, qf0, zero4, 0, 0, 0);
    float4v s1 = __builtin_amdgcn_mfma_f32_16x16x32_bf16(k0, qf1, zero4, 0, 0, 0);
    float4v s2 = __builtin_amdgcn_mfma_f32_16x16x32_bf16(k1, qf0, zero4, 0, 0, 0);
    float4v s3 = __builtin_amdgcn_mfma_f32_16x16x32_bf16(k1, qf1, zero4, 0, 0, 0);
    {
      float p0 = __expf(s0.x), p1 = __expf(s0.y), p2 = __expf(s0.z), p3 = __expf(s0.w);
      rs0 += (p0 + p1) + (p2 + p3);
      uint2 pw; pw.x = pkbf(p0, p1); pw.y = pkbf(p2, p3);
      *reinterpret_cast<uint2*>(&dst[((mbp)*16 + l15) * 140 + nb * 16 + q * 4]) = pw;
    }
    {
      float p0 = __expf(s1.x), p1 = __expf(s1.y), p2 = __expf(s1.z), p3 = __expf(s1.w);
      rs1 += (p0 + p1) + (p2 + p3);
      uint2 pw; pw.x = pkbf(p0, p1); pw.y = pkbf(p2, p3);
      *reinterpret_cast<uint2*>(&dst[((mbp + 1)*16 + l15) * 140 + nb * 16 + q * 4]) = pw;
    }
    {
      float p0 = __expf(s2.x), p1 = __expf(s2.y), p2 = __expf(s2.z), p3 = __expf(s2.w);
      rs0 += (p0 + p1) + (p2 + p3);
      uint2 pw; pw.x = pkbf(p0, p1); pw.y = pkbf(p2, p3);
      *reinterpret_cast<uint2*>(&dst[((mbp)*16 + l15) * 140 + (nb + 4) * 16 + q * 4]) = pw;
    }
    {
      float p0 = __expf(s3.x), p1 = __expf(s3.y), p2 = __expf(s3.z), p3 = __expf(s3.w);
      rs1 += (p0 + p1) + (p2 + p3);
      uint2 pw; pw.x = pkbf(p0, p1); pw.y = pkbf(p2, p3);
      *reinterpret_cast<uint2*>(&dst[((mbp + 1)*16 + l15) * 140 + (nb + 4) * 16 + q * 4]) = pw;
    }
  };

  // ---- prolog: S(0) -> Ps[0]; vc = V(0) part1, kc = K(1) ----
  short8 vc[4];
  #pragma unroll
  for (int ks = 0; ks < 4; ++ks)
    vc[ks] = *reinterpret_cast<const short8*>(Vb + ks * 1024);
  short8 kc0 = *reinterpret_cast<const short8*>(Kb + (size_t)4096);
  short8 kc1 = *reinterpret_cast<const short8*>(Kb + (size_t)4096 + 2048);
  {
    short8 k00 = *reinterpret_cast<const short8*>(Kb);
    short8 k01 = *reinterpret_cast<const short8*>(Kb + 2048);
    s_phase(k00, k01, &sm.Ps[0][0]);
  }
  __syncthreads();

  for (int t = 0; t < 32; ++t) {
    const int buf = t & 1;
    const uint16_t* vt = Vb + (size_t)t * 32768;

    // loads: V(t) part2 (consumed THIS iter, covered by S + PV part1);
    //        V(t+1) part1 + K(t+2) (consumed NEXT iter)
    short8 vp2[4];
    #pragma unroll
    for (int ks = 0; ks < 4; ++ks)
      vp2[ks] = *reinterpret_cast<const short8*>(vt + 16384 + ks * 1024);
    short8 vn[4];
    short8 kn0, kn1;
    if (t < 31) {
      #pragma unroll
      for (int ks = 0; ks < 4; ++ks)
        vn[ks] = *reinterpret_cast<const short8*>(vt + 32768 + ks * 1024);
      kn0 = *reinterpret_cast<const short8*>(Kb + (size_t)(t + 2) * 4096);
      kn1 = *reinterpret_cast<const short8*>(Kb + (size_t)(t + 2) * 4096 + 2048);
    }

    // ---- S(t+1) -> Ps[buf^1] (kc loaded last iter, in registers) ----
    if (t < 31) s_phase(kc0, kc1, &sm.Ps[buf ^ 1][0]);

    // ---- PV(t) part1: ks 0..3 from Ps[buf] cols 0..63, B = vc ----
    #pragma unroll
    for (int ks = 0; ks < 4; ++ks) {
      short8 pa0 = ld8(&sm.Ps[buf][(l31     ) * 140 + ks * 16 + half * 8]);
      short8 pa1 = ld8(&sm.Ps[buf][(32 + l31) * 140 + ks * 16 + half * 8]);
      O[0] = __builtin_amdgcn_mfma_f32_32x32x16_bf16(pa0, vc[ks], O[0], 0, 0, 0);
      O[1] = __builtin_amdgcn_mfma_f32_32x32x16_bf16(pa1, vc[ks], O[1], 0, 0, 0);
    }
    // ---- PV(t) part2: ks 4..7 from cols 64..127, B = vp2 ----
    #pragma unroll
    for (int ks = 0; ks < 4; ++ks) {
      short8 pa0 = ld8(&sm.Ps[buf][(l31     ) * 140 + (ks + 4) * 16 + half * 8]);
      short8 pa1 = ld8(&sm.Ps[buf][(32 + l31) * 140 + (ks + 4) * 16 + half * 8]);
      O[0] = __builtin_amdgcn_mfma_f32_32x32x16_bf16(pa0, vp2[ks], O[0], 0, 0, 0);
      O[1] = __builtin_amdgcn_mfma_f32_32x32x16_bf16(pa1, vp2[ks], O[1], 0, 0, 0);
    }
    __syncthreads();

    // rotate register prefetch buffers
    if (t < 31) {
      #pragma unroll
      for (int ks = 0; ks < 4; ++ks) vc[ks] = vn[ks];
      kc0 = kn0; kc1 = kn1;
    }
  }

  // ---- row sums -> Ls = gamma / rowsum ----
  rs0 += __shfl_xor(rs0, 16); rs0 += __shfl_xor(rs0, 32);
  rs1 += __shfl_xor(rs1, 16); rs1 += __shfl_xor(rs1, 32);
  if (q == 0) {
    atomicAdd(&Ls[(mbp    ) * 16 + l15], rs0);
    atomicAdd(&Ls[(mbp + 1) * 16 + l15], rs1);
  }
  __syncthreads();
  if (tid < 64) Ls[tid] = gamma[0] / Ls[tid];
  __syncthreads();   // Ls ready; all Ps reads done -> Os may overwrite

  // ---- epilogue: O (32x32 D layout) -> Os transpose -> coalesced stores ----
  #pragma unroll
  for (int chunk = 0; chunk < 2; ++chunk) {
    if ((w >> 2) == chunk) {
      int cl = (w & 3) * 32 + l31;
      #pragma unroll
      for (int h = 0; h < 2; ++h)
        #pragma unroll
        for (int reg = 0; reg < 16; ++reg) {
          int m = h * 32 + (reg & 3) + 8 * (reg >> 2) + 4 * half;
          sm.Os[cl * 69 + m] = O[h][reg] * Ls[m];
        }
    }
    __syncthreads();
    {
      int cl = tid >> 2, msub = tid & 3;
      int c = chunk * 128 + cl;
      size_t idx = ((size_t)b * C_ + c) * N_ + m0 + msub * 16;
      const float* os = &sm.Os[cl * 69 + msub * 16];
      #pragma unroll
      for (int i = 0; i < 4; ++i) {
        float4 xv = *reinterpret_cast<const float4*>(x + idx + i * 4);
        float4 ov;
        ov.x = os[i * 4 + 0] + xv.x;
        ov.y = os[i * 4 + 1] + xv.y;
        ov.z = os[i * 4 + 2] + xv.z;
        ov.w = os[i * 4 + 3] + xv.w;
        *reinterpret_cast<float4*>(out + idx + i * 4) = ov;
      }
    }
    __syncthreads();
  }
}

extern "C" void kernel_launch(void* const* d_in, const int* in_sizes, int n_in,
                              void* d_out, int out_size, void* d_ws, size_t ws_size,
                              hipStream_t stream) {
  const float* x     = (const float*)d_in[0];
  const float* Wq    = (const float*)d_in[1];
  const float* bq    = (const float*)d_in[2];
  const float* Wk    = (const float*)d_in[3];
  const float* bk    = (const float*)d_in[4];
  const float* Wv    = (const float*)d_in[5];
  const float* bv    = (const float*)d_in[6];
  const float* gamma = (const float*)d_in[7];
  float* out = (float*)d_out;

  // ws: Qw bf16 2MB | Kw bf16 2MB | Vw bf16 16MB (swizzled) | Wc | bc
  uint16_t* Qw = (uint16_t*)d_ws;
  uint16_t* Kw = Qw + (size_t)B_ * N_ * 32;
  uint16_t* Vw = Kw + (size_t)B_ * N_ * 32;
  uint16_t* Wc = Vw + (size_t)B_ * C_ * N_;
  float*    bc = (float*)(Wc + 320 * 256);

  wconv_kernel<<<80, 256, 0, stream>>>(Wq, bq, Wk, bk, Wv, bv, Wc, bc);
  qkv_mfma<<<512, 512, 0, stream>>>(x, Wc, bc, Qw, Kw, Vw);
  attn_mfma<<<512, 512, 0, stream>>>(Qw, Kw, Vw, x, gamma, out);
}

// Round 8
// 223.110 us; speedup vs baseline: 1.0409x; 1.0409x over previous
//
#include <hip/hip_runtime.h>
#include <stdint.h>

#define B_ 8
#define C_ 256
#define N_ 4096

typedef __attribute__((ext_vector_type(8))) short short8;
typedef __attribute__((ext_vector_type(4))) float float4v;
typedef __attribute__((ext_vector_type(16))) float floatx16;

__device__ __forceinline__ uint16_t f2bfr(float f) {
  return (uint16_t)((__float_as_uint(f) + 0x8000u) >> 16);
}
__device__ __forceinline__ uint32_t pkbf(float lo, float hi) {
  return ((__float_as_uint(hi) + 0x8000u) & 0xffff0000u) |
         ((__float_as_uint(lo) + 0x8000u) >> 16);
}
// 16B LDS read as 2x b64 (rows 152B-strided: dw-stride 38 == 6 mod 32,
// gcd(6,32)=2 -> 2-way bank aliasing == free per m136.)
__device__ __forceinline__ short8 ld8(const uint16_t* p) {
  union { ushort4 h[2]; short8 v; } u;
  u.h[0] = *reinterpret_cast<const ushort4*>(p);
  u.h[1] = *reinterpret_cast<const ushort4*>(p + 4);
  return u.v;
}

// ---------------------------------------------------------------------------
// Kernel 0: W fp32 -> Wc bf16, biases fp32.
// ---------------------------------------------------------------------------
__global__ __launch_bounds__(256) void wconv_kernel(
    const float* __restrict__ Wq, const float* __restrict__ bq,
    const float* __restrict__ Wk, const float* __restrict__ bk,
    const float* __restrict__ Wv, const float* __restrict__ bv,
    uint16_t* __restrict__ Wc, float* __restrict__ bc)
{
  int tg = blockIdx.x * 256 + threadIdx.x;
  int idx = tg * 4;
  const float* src = (idx < 8192) ? (Wq + idx)
                   : (idx < 16384) ? (Wk + (idx - 8192))
                                   : (Wv + (idx - 16384));
  float4 wv = *reinterpret_cast<const float4*>(src);
  uint2 o;
  o.x = pkbf(wv.x, wv.y);
  o.y = pkbf(wv.z, wv.w);
  *reinterpret_cast<uint2*>(Wc + idx) = o;
  if (tg < 320) bc[tg] = (tg < 32) ? bq[tg] : (tg < 64) ? bk[tg - 32] : bv[tg - 64];
}

// ---------------------------------------------------------------------------
// Kernel 1: QKV via MFMA. 1-D grid, XCD-pinned (b = blockIdx.x & 7).
// Round-7/8 change: V epilogue shuffle-merges MFMA D-fragments across the
// 4-lane n-group (lane^1 then lane^2) so each lane stores ONE dwordx2 (8B,
// a 4-wide n-quad of a single channel) instead of 4 scattered 2B stores.
// Store instructions 4x fewer, 4x more bytes per instruction.
// ---------------------------------------------------------------------------
__global__ __launch_bounds__(512, 4) void qkv_mfma(
    const float* __restrict__ x, const uint16_t* __restrict__ Wc,
    const float* __restrict__ bc,
    uint16_t* __restrict__ Qw, uint16_t* __restrict__ Kw, uint16_t* __restrict__ Vw)
{
  __shared__ __align__(16) uint16_t xs[64][268];
  const int b = blockIdx.x & 7;         // XCD pin
  const int tile = blockIdx.x >> 3;
  const int n0 = tile * 64;
  const int tid = threadIdx.x;
  const int nl = tid & 63, grp = tid >> 6;
  const int w = grp, l15 = tid & 15, q = (tid & 63) >> 4;
  const int nb = w & 3;

  const float* xb = x + (size_t)b * C_ * N_ + n0;
  #pragma unroll
  for (int it = 0; it < 16; ++it) {
    int c2 = it * 16 + grp * 2;
    float f0 = xb[(size_t)c2 * N_ + nl];
    float f1 = xb[(size_t)(c2 + 1) * N_ + nl];
    *reinterpret_cast<uint32_t*>(&xs[nl][c2]) = pkbf(f0, f1);
  }
  __syncthreads();

  float4v acc[10];
  #pragma unroll
  for (int i = 0; i < 10; ++i) acc[i] = (float4v){0.f, 0.f, 0.f, 0.f};

  const int ob0 = (w >> 2) * 10;
  #pragma unroll
  for (int h2 = 0; h2 < 2; ++h2) {
    short8 bx[4];
    #pragma unroll
    for (int kb = 0; kb < 4; ++kb)
      bx[kb] = ld8(&xs[nb * 16 + l15][h2 * 128 + kb * 32 + q * 8]);
    #pragma unroll
    for (int oi = 0; oi < 10; ++oi) {
      int ob = ob0 + oi;
      const uint16_t* wr = Wc + (size_t)(ob * 16 + l15) * 256 + h2 * 128 + q * 8;
      short8 aw[4];
      #pragma unroll
      for (int kb = 0; kb < 4; ++kb)
        aw[kb] = *reinterpret_cast<const short8*>(wr + kb * 32);
      #pragma unroll
      for (int kb = 0; kb < 4; ++kb)
        acc[oi] = __builtin_amdgcn_mfma_f32_16x16x32_bf16(aw[kb], bx[kb], acc[oi], 0, 0, 0);
    }
  }

  // ---- Q/K epilogue (ob 0..3 live in waves 0-3) via LDS transpose ----
  __syncthreads();
  uint16_t (*qs)[72] = reinterpret_cast<uint16_t(*)[72]>(&xs[0][0]);
  if (w < 4) {
    #pragma unroll
    for (int oi = 0; oi < 4; ++oi) {
      float4v a = acc[oi];
      const float* bb = bc + oi * 16 + q * 4;
      uint2 pk2;
      pk2.x = pkbf(a.x + bb[0], a.y + bb[1]);
      pk2.y = pkbf(a.z + bb[2], a.w + bb[3]);
      *reinterpret_cast<uint2*>(&qs[nb * 16 + l15][oi * 16 + q * 4]) = pk2;
    }
  }
  __syncthreads();
  if (tid < 256) {
    int n = tid >> 2, sub = tid & 3;
    const uint16_t* row = qs[n];
    uint4 d0 = *reinterpret_cast<const uint4*>(&row[sub * 16]);
    uint4 d1 = *reinterpret_cast<const uint4*>(&row[sub * 16 + 8]);
    size_t nn = (size_t)b * N_ + n0 + n;
    if (sub < 2) {
      uint4* dst = reinterpret_cast<uint4*>(Qw + nn * 32 + sub * 16);
      dst[0] = d0; dst[1] = d1;
    } else {
      uint4* dst = reinterpret_cast<uint4*>(Kw + nn * 32 + (sub - 2) * 16);
      dst[0] = d0; dst[1] = d1;
    }
  }
  // ---- V epilogue into swizzled layout, shuffle-merged 8B stores ----
  // n = nb*16 + l15; j = l15&7. 4-lane group {lane^0,^1,^2,^3} shares
  // (q, half, n-quad) and partitions the 4 c-offsets as {0,2,1,3}:
  //   r1 (lane^1): even-j lanes keep words for c+0,c+1; odd-j for c+2,c+3
  //   r2 (lane^2): each lane keeps ONE c, gains the partner n-pair word.
  const size_t blk = ((size_t)b * 64 + tile) * 4;
  const int half = l15 >> 3;
  const int podd = l15 & 1, s2 = (l15 >> 1) & 1;
  const int nq = (l15 & 7) & ~3;                 // n-quad base within 8
  #pragma unroll
  for (int oi = 0; oi < 10; ++oi) {
    int ob = ob0 + oi;
    if (ob < 4) continue;
    float4v a = acc[oi];
    const float* bb = bc + ob * 16 + q * 4;
    int cb = ob * 16 - 64 + q * 4;
    float v0 = a.x + bb[0], v1 = a.y + bb[1];
    float v2 = a.z + bb[2], v3 = a.w + bb[3];
    // r1: exchange with n-neighbor
    float t0 = __shfl_xor(v0, 1), t1 = __shfl_xor(v1, 1);
    float t2 = __shfl_xor(v2, 1), t3 = __shfl_xor(v3, 1);
    // wA: c = cb + 2*podd ; wB: c = cb + 2*podd + 1 ; both cover n-pair (n&~1, n|1)
    uint32_t wA = podd ? pkbf(t2, v2) : pkbf(v0, t0);
    uint32_t wB = podd ? pkbf(t3, v3) : pkbf(v1, t1);
    // r2: exchange words with n-pair neighbor
    uint32_t uA = __shfl_xor(wA, 2), uB = __shfl_xor(wB, 2);
    uint2 st;
    int cfin;
    if (!s2) { st.x = wA; st.y = uA; cfin = cb + 2 * podd; }      // n: nq..nq+3
    else     { st.x = uB; st.y = wB; cfin = cb + 2 * podd + 1; }
    size_t vaddr = (blk + (cfin >> 6)) * 4096
                 + (size_t)(nb * 1024 + ((cfin >> 5) & 1) * 512 + half * 256
                            + (cfin & 31) * 8 + nq);
    *reinterpret_cast<uint2*>(Vw + vaddr) = st;
  }
}

// ---------------------------------------------------------------------------
// Kernel 2: MFMA flash attention. 512 thr, grid 512, XCD-pinned.
// ROUND-4 BODY VERBATIM (best measured: 96.5-97.4us, MfmaUtil 37.5).
// Post-mortems: R5 hand ping-pong 97->103 FAILED; R6 KVBLK=128 (half the
// barriers) 97->103.5 FAILED -> barriers, rotation movs, and LDS conflicts
// are all exonerated; this schedule is a local optimum for this structure.
// Register prefetch distance = 1 iter (R3-validated); Ps rows 76 uint16
// (152B, free 2-way bank class).
// ---------------------------------------------------------------------------
__global__ __launch_bounds__(512, 4) void attn_mfma(
    const uint16_t* __restrict__ Qw, const uint16_t* __restrict__ Kw,
    const uint16_t* __restrict__ Vw, const float* __restrict__ x,
    const float* __restrict__ gamma, float* __restrict__ out)
{
  __shared__ __align__(16) union Smem {
    uint16_t Ps[2][64 * 76];      // 19456 B, rows 152B (38 dw == 6 mod 32)
    float Os[128 * 69];           // 35328 B, stride 69 == 5 mod 32
  } sm;
  __shared__ float Ls[64];

  const int b = blockIdx.x & 7;         // XCD pin (matches qkv)
  const int m0 = (blockIdx.x >> 3) * 64;
  const int tid = threadIdx.x;
  const int w = tid >> 6, lane = tid & 63;
  const int l15 = lane & 15, q = lane >> 4;
  const int l31 = lane & 31, half = lane >> 5;
  const int nb = w & 3, mbp = (w >> 2) * 2;     // S assignment

  const uint16_t* Kb = Kw + (size_t)b * N_ * 32 + (size_t)(nb * 16 + l15) * 32 + q * 8;
  const short8 qf0 = *reinterpret_cast<const short8*>(
      Qw + ((size_t)b * N_ + m0 + (mbp    ) * 16 + l15) * 32 + q * 8);
  const short8 qf1 = *reinterpret_cast<const short8*>(
      Qw + ((size_t)b * N_ + m0 + (mbp + 1) * 16 + l15) * 32 + q * 8);
  // swizzled V: lane offset within (b, tile, cg) 4096-elem block
  const uint16_t* Vb = Vw + ((size_t)b * 256 + (w >> 1)) * 4096
                     + (w & 1) * 512 + half * 256 + l31 * 8;

  floatx16 O[2];
  #pragma unroll
  for (int i = 0; i < 16; ++i) { O[0][i] = 0.f; O[1][i] = 0.f; }
  float rs0 = 0.f, rs1 = 0.f;
  const float4v zero4 = (float4v){0.f, 0.f, 0.f, 0.f};
  if (tid < 64) Ls[tid] = 0.f;

  // ---- prolog: S[0] -> Ps[0]; preload vc = V(0), kc = K(1) ----
  short8 vc[4];
  #pragma unroll
  for (int ks = 0; ks < 4; ++ks)
    vc[ks] = *reinterpret_cast<const short8*>(Vb + ks * 1024);
  short8 kc = *reinterpret_cast<const short8*>(Kb + (size_t)64 * 32);
  {
    short8 kf = *reinterpret_cast<const short8*>(Kb);
    float4v s0 = __builtin_amdgcn_mfma_f32_16x16x32_bf16(kf, qf0, zero4, 0, 0, 0);
    float4v s1 = __builtin_amdgcn_mfma_f32_16x16x32_bf16(kf, qf1, zero4, 0, 0, 0);
    float p0 = __expf(s0.x), p1 = __expf(s0.y), p2 = __expf(s0.z), p3 = __expf(s0.w);
    rs0 += (p0 + p1) + (p2 + p3);
    uint2 pw; pw.x = pkbf(p0, p1); pw.y = pkbf(p2, p3);
    *reinterpret_cast<uint2*>(&sm.Ps[0][((mbp)*16 + l15) * 76 + nb * 16 + q * 4]) = pw;
    float r0 = __expf(s1.x), r1 = __expf(s1.y), r2 = __expf(s1.z), r3 = __expf(s1.w);
    rs1 += (r0 + r1) + (r2 + r3);
    uint2 rw; rw.x = pkbf(r0, r1); rw.y = pkbf(r2, r3);
    *reinterpret_cast<uint2*>(&sm.Ps[0][((mbp + 1)*16 + l15) * 76 + nb * 16 + q * 4]) = rw;
  }
  __syncthreads();

  for (int t = 0; t < 64; ++t) {
    const int buf = t & 1;

    // issue NEXT-iter loads (consumed next iteration -> full-iter latency cover)
    short8 vn[4];
    if (t < 63) {
      const uint16_t* vt = Vb + (size_t)(t + 1) * 16384;
      #pragma unroll
      for (int ks = 0; ks < 4; ++ks)
        vn[ks] = *reinterpret_cast<const short8*>(vt + ks * 1024);
    }
    short8 kn;
    if (t < 62)
      kn = *reinterpret_cast<const short8*>(Kb + (size_t)(t + 2) * 64 * 32);

    // ---- S[t+1] -> Ps[buf^1] (kc loaded last iter, already in registers) ----
    if (t < 63) {
      float4v s0 = __builtin_amdgcn_mfma_f32_16x16x32_bf16(kc, qf0, zero4, 0, 0, 0);
      float4v s1 = __builtin_amdgcn_mfma_f32_16x16x32_bf16(kc, qf1, zero4, 0, 0, 0);
      float p0 = __expf(s0.x), p1 = __expf(s0.y), p2 = __expf(s0.z), p3 = __expf(s0.w);
      rs0 += (p0 + p1) + (p2 + p3);
      uint2 pw; pw.x = pkbf(p0, p1); pw.y = pkbf(p2, p3);
      *reinterpret_cast<uint2*>(&sm.Ps[buf ^ 1][((mbp)*16 + l15) * 76 + nb * 16 + q * 4]) = pw;
      float r0 = __expf(s1.x), r1 = __expf(s1.y), r2 = __expf(s1.z), r3 = __expf(s1.w);
      rs1 += (r0 + r1) + (r2 + r3);
      uint2 rw; rw.x = pkbf(r0, r1); rw.y = pkbf(r2, r3);
      *reinterpret_cast<uint2*>(&sm.Ps[buf ^ 1][((mbp + 1)*16 + l15) * 76 + nb * 16 + q * 4]) = rw;
    }

    // ---- PV[t]: A = Ps[buf] via 2xb64 (both m-halves), B = vc (registers) ----
    #pragma unroll
    for (int ks = 0; ks < 4; ++ks) {
      short8 pa0 = ld8(&sm.Ps[buf][(l31     ) * 76 + ks * 16 + half * 8]);
      short8 pa1 = ld8(&sm.Ps[buf][(32 + l31) * 76 + ks * 16 + half * 8]);
      O[0] = __builtin_amdgcn_mfma_f32_32x32x16_bf16(pa0, vc[ks], O[0], 0, 0, 0);
      O[1] = __builtin_amdgcn_mfma_f32_32x32x16_bf16(pa1, vc[ks], O[1], 0, 0, 0);
    }
    __syncthreads();

    // rotate register prefetch buffers
    if (t < 63) {
      #pragma unroll
      for (int ks = 0; ks < 4; ++ks) vc[ks] = vn[ks];
    }
    if (t < 62) kc = kn;
  }

  // ---- row sums -> Ls = gamma / rowsum ----
  rs0 += __shfl_xor(rs0, 16); rs0 += __shfl_xor(rs0, 32);
  rs1 += __shfl_xor(rs1, 16); rs1 += __shfl_xor(rs1, 32);
  if (q == 0) {
    atomicAdd(&Ls[(mbp    ) * 16 + l15], rs0);
    atomicAdd(&Ls[(mbp + 1) * 16 + l15], rs1);
  }
  __syncthreads();
  if (tid < 64) Ls[tid] = gamma[0] / Ls[tid];
  __syncthreads();   // Ls ready; all Ps reads done -> Os may overwrite

  // ---- epilogue: O (32x32 D layout) -> Os transpose -> coalesced stores ----
  #pragma unroll
  for (int chunk = 0; chunk < 2; ++chunk) {
    if ((w >> 2) == chunk) {
      int cl = (w & 3) * 32 + l31;
      #pragma unroll
      for (int h = 0; h < 2; ++h)
        #pragma unroll
        for (int reg = 0; reg < 16; ++reg) {
          int m = h * 32 + (reg & 3) + 8 * (reg >> 2) + 4 * half;
          sm.Os[cl * 69 + m] = O[h][reg] * Ls[m];
        }
    }
    __syncthreads();
    {
      int cl = tid >> 2, msub = tid & 3;
      int c = chunk * 128 + cl;
      size_t idx = ((size_t)b * C_ + c) * N_ + m0 + msub * 16;
      const float* os = &sm.Os[cl * 69 + msub * 16];
      #pragma unroll
      for (int i = 0; i < 4; ++i) {
        float4 xv = *reinterpret_cast<const float4*>(x + idx + i * 4);
        float4 ov;
        ov.x = os[i * 4 + 0] + xv.x;
        ov.y = os[i * 4 + 1] + xv.y;
        ov.z = os[i * 4 + 2] + xv.z;
        ov.w = os[i * 4 + 3] + xv.w;
        *reinterpret_cast<float4*>(out + idx + i * 4) = ov;
      }
    }
    __syncthreads();
  }
}

extern "C" void kernel_launch(void* const* d_in, const int* in_sizes, int n_in,
                              void* d_out, int out_size, void* d_ws, size_t ws_size,
                              hipStream_t stream) {
  const float* x     = (const float*)d_in[0];
  const float* Wq    = (const float*)d_in[1];
  const float* bq    = (const float*)d_in[2];
  const float* Wk    = (const float*)d_in[3];
  const float* bk    = (const float*)d_in[4];
  const float* Wv    = (const float*)d_in[5];
  const float* bv    = (const float*)d_in[6];
  const float* gamma = (const float*)d_in[7];
  float* out = (float*)d_out;

  // ws: Qw bf16 2MB | Kw bf16 2MB | Vw bf16 16MB (swizzled) | Wc | bc
  uint16_t* Qw = (uint16_t*)d_ws;
  uint16_t* Kw = Qw + (size_t)B_ * N_ * 32;
  uint16_t* Vw = Kw + (size_t)B_ * N_ * 32;
  uint16_t* Wc = Vw + (size_t)B_ * C_ * N_;
  float*    bc = (float*)(Wc + 320 * 256);

  wconv_kernel<<<80, 256, 0, stream>>>(Wq, bq, Wk, bk, Wv, bv, Wc, bc);
  qkv_mfma<<<512, 512, 0, stream>>>(x, Wc, bc, Qw, Kw, Vw);
  attn_mfma<<<512, 512, 0, stream>>>(Qw, Kw, Vw, x, gamma, out);
}